// Round 14
// baseline (16.658 us; speedup 1.0000x reference)
//
#include <hip/hip_runtime.h>

typedef float f32x2 __attribute__((ext_vector_type(2)));
typedef float f32x4 __attribute__((ext_vector_type(4)));
typedef short bf16x8 __attribute__((ext_vector_type(8)));

#define HW 65536
#define WIMG 256
#define KK 1024
#define KG 32           // 32x32 control grid, spacing 255/31
#define TPB 256         // 4 waves per tile

__device__ __forceinline__ int rect_origin(int t0) {
    const int n = t0 - 24;
    return (n > 0) ? min((n * (KG - 1) + 254) / 255, KG - 8) : 0;
}
// hardware packed f32x2 -> bf16x2 (RNE)
__device__ __forceinline__ unsigned pk2(float lo, float hi) {
    unsigned r;
    asm("v_cvt_pk_bf16_f32 %0, %1, %2" : "=v"(r) : "v"(lo), "v"(hi));
    return r;
}
__device__ __forceinline__ float cgrid(int i) {   // np.linspace(0,255,32)[i]
    return (float)((double)i * (255.0 / 31.0));
}

__global__ __launch_bounds__(TPB, 4) void rbf_mfma(
    const float2* __restrict__ loc2,   // cpoint_loc (B,K,2)
    const float2* __restrict__ alp2,   // alpha      (B,K,2)
    float* __restrict__ out)           // (B,2,H,W)
{
    __shared__ uint4 Ut4[512];          // 8 KB: Ut, 16 rows x 512 B (swizzled)
    __shared__ float sred[16][68];      // 4.25 KB: store-transpose buffer
    char* const base = (char*)Ut4;

    const int tid = threadIdx.x;
    const int bx = blockIdx.x & (KG - 1);
    const int by = blockIdx.x >> 5;
    const int x0 = bx * 8, y0 = by * 8;
    const int r0x = rect_origin(x0), r0y = rect_origin(y0);

    // ---- build Ut[n][k] straight from global tables (L2-hot gathers) ----
    {
        const int b   = tid & 7;
        const int q   = tid >> 3;        // 0..31
        const int gy  = q >> 2;          // cp row in rect
        const int gx0 = (q & 3) * 2;     // cp col of e=2q
        const int kbase = b * KK + (r0y + gy) * KG + r0x + gx0;
        const float2 l0 = loc2[kbase];
        const float2 l1 = loc2[kbase + 1];
        const float2 a0 = alp2[kbase];
        const float2 a1 = alp2[kbase + 1];
        const float cpy  = cgrid(r0y + gy);
        const float cpx0 = cgrid(r0x + gx0);
        const float cpx1 = cgrid(r0x + gx0 + 1);
        const float dlx0 = l0.x - cpx0, dly0 = l0.y - cpy;
        const float dlx1 = l1.x - cpx1, dly1 = l1.y - cpy;
        const int n0 = 2 * b, n1 = 2 * b + 1;
        const uint4 w0 = make_uint4(                 // c=0 plane: ax
            pk2(a0.x, dlx0 * a0.x), pk2(dly0 * a0.x, 0.0f),
            pk2(a1.x, dlx1 * a1.x), pk2(dly1 * a1.x, 0.0f));
        const uint4 w1 = make_uint4(                 // c=1 plane: ay
            pk2(a0.y, dlx0 * a0.y), pk2(dly0 * a0.y, 0.0f),
            pk2(a1.y, dlx1 * a1.y), pk2(dly1 * a1.y, 0.0f));
        *(uint4*)(base + ((n0 * 512 + 16 * q) ^ ((n0 & 7) << 4))) = w0;
        *(uint4*)(base + ((n1 * 512 + 16 * q) ^ ((n1 & 7) << 4))) = w1;
    }
    __syncthreads();

    const int wv   = tid >> 6;           // m-tile 0..3
    const int lane = tid & 63;
    const int row  = lane & 15;          // A row within m-tile / B col (n)
    const int ch   = lane >> 4;          // k-chunk 0..3

    // ---- prefetch ALL B-fragments into registers ----
    bf16x8 bv0, bv1, bv2, bv3, bv4, bv5, bv6, bv7;
    {
        const int rb = row * 512 + ch * 16;
        const int sw = (row & 7) << 4;
        bv0 = *(const bf16x8*)(base + ((rb + 0 * 64) ^ sw));
        bv1 = *(const bf16x8*)(base + ((rb + 1 * 64) ^ sw));
        bv2 = *(const bf16x8*)(base + ((rb + 2 * 64) ^ sw));
        bv3 = *(const bf16x8*)(base + ((rb + 3 * 64) ^ sw));
        bv4 = *(const bf16x8*)(base + ((rb + 4 * 64) ^ sw));
        bv5 = *(const bf16x8*)(base + ((rb + 5 * 64) ^ sw));
        bv6 = *(const bf16x8*)(base + ((rb + 6 * 64) ^ sw));
        bv7 = *(const bf16x8*)(base + ((rb + 7 * 64) ^ sw));
    }

    // ---- fused geometry (packed f32x2) -> register A-fragment -> MFMA ----
    const float fx = (float)(x0 + (lane & 7));
    const float fy = (float)(y0 + wv * 2 + ((lane >> 3) & 1));
    const f32x2 dxp = {cgrid(r0x + 2 * ch) - fx, cgrid(r0x + 2 * ch + 1) - fx};
    float dy = cgrid(r0y) - fy;                      // exact at kk=0
    const float DELTA = (float)(255.0 / 31.0);

    f32x4 acc = {0.f, 0.f, 0.f, 0.f};
#define STEP(BV)                                                              \
    {                                                                         \
        const float dy2 = dy * dy;                                            \
        const f32x2 dy2p = {dy2, dy2};                                        \
        const f32x2 d2p = __builtin_elementwise_fma(dxp, dxp, dy2p);          \
        const f32x2 sp = {__builtin_amdgcn_sqrtf(d2p[0]),                     \
                          __builtin_amdgcn_sqrtf(d2p[1])};                    \
        const f32x2 omr = __builtin_elementwise_fma(                          \
            sp, (f32x2)(-1.0f / 24.0f), (f32x2)1.0f);                         \
        const f32x2 omp = __builtin_elementwise_max(omr, (f32x2)0.0f);        \
        const f32x2 om2 = omp * omp;                                          \
        const f32x2 om3 = om2 * omp;                                          \
        const f32x2 om4 = om2 * om2;                                          \
        const f32x2 fp  = __builtin_elementwise_fma(                          \
            sp, (f32x2)(1.0f / 6.0f), (f32x2)1.0f);                           \
        const f32x2 phip = om4 * fp;                                          \
        const f32x2 ggp  = om3 * (f32x2)(-20.0f / 576.0f);                    \
        const f32x2 gdxp = ggp * dxp;                                         \
        const f32x2 gdyp = ggp * (f32x2){dy, dy};                             \
        const uint4 a4 = make_uint4(                                          \
            pk2(phip[0], gdxp[0]), pk2(gdyp[0], 0.0f),                        \
            pk2(phip[1], gdxp[1]), pk2(gdyp[1], 0.0f));                       \
        acc = __builtin_amdgcn_mfma_f32_16x16x32_bf16(                        \
            __builtin_bit_cast(bf16x8, a4), BV, acc, 0, 0, 0);                \
        dy += DELTA;                                                          \
    }
    STEP(bv0) STEP(bv1) STEP(bv2) STEP(bv3)
    STEP(bv4) STEP(bv5) STEP(bv6) STEP(bv7)
#undef STEP

    // ---- coalescing epilogue: acc -> LDS transpose -> float4 stores ----
    *(f32x4*)&sred[row][wv * 16 + ch * 4] = acc;
    __syncthreads();
    {
        const int n   = tid >> 4;        // plane 0..15
        const int seg = tid & 15;        // 4-px segment
        const f32x4 v = *(const f32x4*)&sred[n][seg * 4];
        const int px  = seg * 4;
        const int pix = (y0 + (px >> 3)) * WIMG + x0 + (px & 7);
        *(float4*)&out[n * HW + pix] = make_float4(v[0], v[1], v[2], v[3]);
    }
}

extern "C" void kernel_launch(void* const* d_in, const int* in_sizes, int n_in,
                              void* d_out, int out_size, void* d_ws, size_t ws_size,
                              hipStream_t stream) {
    const float2* cpoint_loc = (const float2*)d_in[0];
    const float2* alpha      = (const float2*)d_in[1];
    float* out = (float*)d_out;

    rbf_mfma<<<KG * KG, TPB, 0, stream>>>(cpoint_loc, alpha, out);
}

// Round 15
// 10.450 us; speedup vs baseline: 1.5940x; 1.5940x over previous
//
#include <hip/hip_runtime.h>

typedef float f32x4 __attribute__((ext_vector_type(4)));
typedef short bf16x8 __attribute__((ext_vector_type(8)));

#define HW 65536
#define WIMG 256
#define KK 1024
#define KG 32           // 32x32 control grid, spacing 255/31
#define TPB 512         // 8 waves per tile: (kgrp 0/1) x (m-tile 0..3)
#define RSTR 20         // padded float stride for the k-merge buffer

__device__ __forceinline__ int rect_origin(int t0) {
    const int n = t0 - 24;
    return (n > 0) ? min((n * (KG - 1) + 254) / 255, KG - 8) : 0;
}
// hardware packed f32x2 -> bf16x2 (RNE)
__device__ __forceinline__ unsigned pk2(float lo, float hi) {
    unsigned r;
    asm("v_cvt_pk_bf16_f32 %0, %1, %2" : "=v"(r) : "v"(lo), "v"(hi));
    return r;
}
__device__ __forceinline__ float cgrid(int i) {   // np.linspace(0,255,32)[i]
    return (float)((double)i * (255.0 / 31.0));
}

__global__ __launch_bounds__(TPB, 8) void rbf_mfma(
    const float2* __restrict__ loc2,   // cpoint_loc (B,K,2)
    const float2* __restrict__ alp2,   // alpha      (B,K,2)
    float* __restrict__ out)           // (B,2,H,W)
{
    __shared__ uint4 Ut4[512];          // 8 KB: Ut, 16 rows x 512 B (swizzled)
    __shared__ float red[64 * RSTR];    // 5 KB: kgrp=1 partial accs
    __shared__ float sred[16][68];      // 4.25 KB: store-transpose buffer
    char* const base = (char*)Ut4;

    const int tid = threadIdx.x;
    const int bx = blockIdx.x & (KG - 1);
    const int by = blockIdx.x >> 5;
    const int x0 = bx * 8, y0 = by * 8;
    const int r0x = rect_origin(x0), r0y = rect_origin(y0);

    // ---- build Ut[n][k]: 512 threads, one cp x two planes each ----
    {
        const int b = tid & 7;
        const int e = tid >> 3;          // cp within rect 0..63
        const int k = b * KK + (r0y + (e >> 3)) * KG + r0x + (e & 7);
        const float2 l = loc2[k];
        const float2 a = alp2[k];
        const float dlx = l.x - cgrid(r0x + (e & 7));
        const float dly = l.y - cgrid(r0y + (e >> 3));
        const int n0 = 2 * b, n1 = 2 * b + 1;
        *(uint2*)(base + ((n0 * 512 + 8 * e) ^ ((n0 & 7) << 4))) =
            make_uint2(pk2(a.x, dlx * a.x), pk2(dly * a.x, 0.0f));
        *(uint2*)(base + ((n1 * 512 + 8 * e) ^ ((n1 & 7) << 4))) =
            make_uint2(pk2(a.y, dlx * a.y), pk2(dly * a.y, 0.0f));
    }
    __syncthreads();

    const int wv   = tid >> 6;           // 0..7
    const int kgrp = wv >> 2;            // 0/1: cp rows kgrp*4 .. +3
    const int mt   = wv & 3;             // m-tile (px rows mt*16..mt*16+15)
    const int lane = tid & 63;
    const int row  = lane & 15;          // A row within m-tile / B col (n)
    const int ch   = lane >> 4;          // k-chunk 0..3

    // ---- prefetch this wave's 4 B-fragments ----
    bf16x8 bv0, bv1, bv2, bv3;
    {
        const int rb = row * 512 + kgrp * 4 * 64 + ch * 16;
        const int sw = (row & 7) << 4;
        bv0 = *(const bf16x8*)(base + ((rb + 0 * 64) ^ sw));
        bv1 = *(const bf16x8*)(base + ((rb + 1 * 64) ^ sw));
        bv2 = *(const bf16x8*)(base + ((rb + 2 * 64) ^ sw));
        bv3 = *(const bf16x8*)(base + ((rb + 3 * 64) ^ sw));
    }

    // ---- fused geometry -> register A-fragment -> MFMA (4 cp rows) ----
    const float fx = (float)(x0 + (lane & 7));
    const float fy = (float)(y0 + mt * 2 + ((lane >> 3) & 1));
    const float dx0 = cgrid(r0x + 2 * ch) - fx;
    const float dx1 = cgrid(r0x + 2 * ch + 1) - fx;
    float dy = cgrid(r0y + kgrp * 4) - fy;
    const float DELTA = (float)(255.0 / 31.0);

    f32x4 acc = {0.f, 0.f, 0.f, 0.f};
#define STEP(BV)                                                              \
    {                                                                         \
        const float dy2  = dy * dy;                                           \
        const float d2a  = fmaf(dx0, dx0, dy2);                               \
        const float sa   = __builtin_amdgcn_sqrtf(d2a);                       \
        const float oma  = fmaxf(fmaf(sa, -1.0f / 24.0f, 1.0f), 0.0f);        \
        const float oma2 = oma * oma;                                         \
        const float phia = (oma2 * oma2) * fmaf(sa, 1.0f / 6.0f, 1.0f);       \
        const float gga  = (oma2 * oma) * (-20.0f / 576.0f);                  \
        const float d2b  = fmaf(dx1, dx1, dy2);                               \
        const float sb   = __builtin_amdgcn_sqrtf(d2b);                       \
        const float omb  = fmaxf(fmaf(sb, -1.0f / 24.0f, 1.0f), 0.0f);        \
        const float omb2 = omb * omb;                                         \
        const float phib = (omb2 * omb2) * fmaf(sb, 1.0f / 6.0f, 1.0f);       \
        const float ggb  = (omb2 * omb) * (-20.0f / 576.0f);                  \
        const uint4 a4 = make_uint4(                                          \
            pk2(phia, gga * dx0), pk2(gga * dy, 0.0f),                        \
            pk2(phib, ggb * dx1), pk2(ggb * dy, 0.0f));                       \
        acc = __builtin_amdgcn_mfma_f32_16x16x32_bf16(                        \
            __builtin_bit_cast(bf16x8, a4), BV, acc, 0, 0, 0);                \
        dy += DELTA;                                                          \
    }
    STEP(bv0) STEP(bv1) STEP(bv2) STEP(bv3)
#undef STEP

    // ---- merge k-halves: kgrp=1 publishes, kgrp=0 accumulates ----
    if (kgrp == 1)
        *(f32x4*)&red[(mt * 16 + row) * RSTR + ch * 4] = acc;
    __syncthreads();
    if (kgrp == 0) {
        const f32x4 p = *(const f32x4*)&red[(mt * 16 + row) * RSTR + ch * 4];
        acc += p;
        // coalescing epilogue stage 1: transpose into sred
        *(f32x4*)&sred[row][mt * 16 + ch * 4] = acc;
    }
    __syncthreads();

    // ---- stage 2: contiguous float4 stores (first 256 threads) ----
    if (tid < 256) {
        const int n   = tid >> 4;        // plane 0..15
        const int seg = tid & 15;        // 4-px segment
        const f32x4 v = *(const f32x4*)&sred[n][seg * 4];
        const int px  = seg * 4;
        const int pix = (y0 + (px >> 3)) * WIMG + x0 + (px & 7);
        *(float4*)&out[n * HW + pix] = make_float4(v[0], v[1], v[2], v[3]);
    }
}

extern "C" void kernel_launch(void* const* d_in, const int* in_sizes, int n_in,
                              void* d_out, int out_size, void* d_ws, size_t ws_size,
                              hipStream_t stream) {
    const float2* cpoint_loc = (const float2*)d_in[0];
    const float2* alpha      = (const float2*)d_in[1];
    float* out = (float*)d_out;

    rbf_mfma<<<KG * KG, TPB, 0, stream>>>(cpoint_loc, alpha, out);
}

// Round 16
// 10.404 us; speedup vs baseline: 1.6011x; 1.0044x over previous
//
#include <hip/hip_runtime.h>

typedef float f32x4 __attribute__((ext_vector_type(4)));
typedef short bf16x8 __attribute__((ext_vector_type(8)));

#define HW 65536
#define WIMG 256
#define KK 1024
#define KG 32           // 32x32 control grid, spacing 255/31
#define TPB 512         // 8 waves per tile: (kgrp 0/1) x (m-tile 0..3)
#define RSTR 20         // padded float stride for the k-merge buffer

__device__ __forceinline__ int rect_origin(int t0) {
    const int n = t0 - 24;
    return (n > 0) ? min((n * (KG - 1) + 254) / 255, KG - 8) : 0;
}
// hardware packed f32x2 -> bf16x2 (RNE)
__device__ __forceinline__ unsigned pk2(float lo, float hi) {
    unsigned r;
    asm("v_cvt_pk_bf16_f32 %0, %1, %2" : "=v"(r) : "v"(lo), "v"(hi));
    return r;
}
__device__ __forceinline__ float cgrid(int i) {   // np.linspace(0,255,32)[i]
    return (float)((double)i * (255.0 / 31.0));
}

__global__ __launch_bounds__(TPB, 8) void rbf_mfma(
    const float2* __restrict__ loc2,   // cpoint_loc (B,K,2)
    const float2* __restrict__ alp2,   // alpha      (B,K,2)
    float* __restrict__ out)           // (B,2,H,W)
{
    __shared__ uint4 Ut4[512];          // 8 KB: Ut, 16 rows x 512 B (swizzled)
    __shared__ float red[64 * RSTR];    // 5 KB: kgrp=1 partial accs
    __shared__ float sred[16][68];      // 4.25 KB: store-transpose buffer
    char* const base = (char*)Ut4;

    const int tid = threadIdx.x;
    const int bx = blockIdx.x & (KG - 1);
    const int by = blockIdx.x >> 5;
    const int x0 = bx * 8, y0 = by * 8;
    const int r0x = rect_origin(x0), r0y = rect_origin(y0);

    const int wv   = tid >> 6;           // 0..7
    const int kgrp = wv >> 2;            // 0/1: cp rows kgrp*4 .. +3
    const int mt   = wv & 3;             // m-tile (px rows mt*16..mt*16+15)
    const int lane = tid & 63;
    const int row  = lane & 15;          // A row within m-tile / B col (n)
    const int ch   = lane >> 4;          // k-chunk 0..3

    // ---- phase A1: ISSUE table gathers (cold memory after poison fill) ----
    const int b = tid & 7;
    const int e = tid >> 3;              // cp within rect 0..63
    const int k = b * KK + (r0y + (e >> 3)) * KG + r0x + (e & 7);
    const float2 l = loc2[k];
    const float2 a = alp2[k];

    // ---- phase A2: geometry -> A-fragments in registers (NO dependence on
    //      the loads above: the whole cold-miss latency hides under this) ----
    const float fx = (float)(x0 + (lane & 7));
    const float fy = (float)(y0 + mt * 2 + ((lane >> 3) & 1));
    const float dx0 = cgrid(r0x + 2 * ch) - fx;
    const float dx1 = cgrid(r0x + 2 * ch + 1) - fx;
    float dy = cgrid(r0y + kgrp * 4) - fy;
    const float DELTA = (float)(255.0 / 31.0);

    uint4 A0, A1, A2, A3;
#define GEO(AOUT)                                                             \
    {                                                                         \
        const float dy2  = dy * dy;                                           \
        const float d2a  = fmaf(dx0, dx0, dy2);                               \
        const float sa   = __builtin_amdgcn_sqrtf(d2a);                       \
        const float oma  = fmaxf(fmaf(sa, -1.0f / 24.0f, 1.0f), 0.0f);        \
        const float oma2 = oma * oma;                                         \
        const float phia = (oma2 * oma2) * fmaf(sa, 1.0f / 6.0f, 1.0f);       \
        const float gga  = (oma2 * oma) * (-20.0f / 576.0f);                  \
        const float d2b  = fmaf(dx1, dx1, dy2);                               \
        const float sb   = __builtin_amdgcn_sqrtf(d2b);                       \
        const float omb  = fmaxf(fmaf(sb, -1.0f / 24.0f, 1.0f), 0.0f);        \
        const float omb2 = omb * omb;                                         \
        const float phib = (omb2 * omb2) * fmaf(sb, 1.0f / 6.0f, 1.0f);       \
        const float ggb  = (omb2 * omb) * (-20.0f / 576.0f);                  \
        AOUT = make_uint4(                                                    \
            pk2(phia, gga * dx0), pk2(gga * dy, 0.0f),                        \
            pk2(phib, ggb * dx1), pk2(ggb * dy, 0.0f));                       \
        dy += DELTA;                                                          \
    }
    GEO(A0) GEO(A1) GEO(A2) GEO(A3)
#undef GEO

    // ---- phase A3: consume table loads -> Ut build + LDS write ----
    {
        const float dlx = l.x - cgrid(r0x + (e & 7));
        const float dly = l.y - cgrid(r0y + (e >> 3));
        const int n0 = 2 * b, n1 = 2 * b + 1;
        *(uint2*)(base + ((n0 * 512 + 8 * e) ^ ((n0 & 7) << 4))) =
            make_uint2(pk2(a.x, dlx * a.x), pk2(dly * a.x, 0.0f));
        *(uint2*)(base + ((n1 * 512 + 8 * e) ^ ((n1 & 7) << 4))) =
            make_uint2(pk2(a.y, dlx * a.y), pk2(dly * a.y, 0.0f));
    }
    __syncthreads();

    // ---- phase B: read this wave's 4 B-fragments ----
    bf16x8 bv0, bv1, bv2, bv3;
    {
        const int rb = row * 512 + kgrp * 4 * 64 + ch * 16;
        const int sw = (row & 7) << 4;
        bv0 = *(const bf16x8*)(base + ((rb + 0 * 64) ^ sw));
        bv1 = *(const bf16x8*)(base + ((rb + 1 * 64) ^ sw));
        bv2 = *(const bf16x8*)(base + ((rb + 2 * 64) ^ sw));
        bv3 = *(const bf16x8*)(base + ((rb + 3 * 64) ^ sw));
    }

    // ---- phase C: 4 MFMAs ----
    f32x4 acc = {0.f, 0.f, 0.f, 0.f};
    acc = __builtin_amdgcn_mfma_f32_16x16x32_bf16(
        __builtin_bit_cast(bf16x8, A0), bv0, acc, 0, 0, 0);
    acc = __builtin_amdgcn_mfma_f32_16x16x32_bf16(
        __builtin_bit_cast(bf16x8, A1), bv1, acc, 0, 0, 0);
    acc = __builtin_amdgcn_mfma_f32_16x16x32_bf16(
        __builtin_bit_cast(bf16x8, A2), bv2, acc, 0, 0, 0);
    acc = __builtin_amdgcn_mfma_f32_16x16x32_bf16(
        __builtin_bit_cast(bf16x8, A3), bv3, acc, 0, 0, 0);

    // ---- merge k-halves: kgrp=1 publishes, kgrp=0 accumulates ----
    if (kgrp == 1)
        *(f32x4*)&red[(mt * 16 + row) * RSTR + ch * 4] = acc;
    __syncthreads();
    if (kgrp == 0) {
        const f32x4 p = *(const f32x4*)&red[(mt * 16 + row) * RSTR + ch * 4];
        acc += p;
        *(f32x4*)&sred[row][mt * 16 + ch * 4] = acc;
    }
    __syncthreads();

    // ---- contiguous float4 stores (first 256 threads) ----
    if (tid < 256) {
        const int n   = tid >> 4;        // plane 0..15
        const int seg = tid & 15;        // 4-px segment
        const f32x4 v = *(const f32x4*)&sred[n][seg * 4];
        const int px  = seg * 4;
        const int pix = (y0 + (px >> 3)) * WIMG + x0 + (px & 7);
        *(float4*)&out[n * HW + pix] = make_float4(v[0], v[1], v[2], v[3]);
    }
}

extern "C" void kernel_launch(void* const* d_in, const int* in_sizes, int n_in,
                              void* d_out, int out_size, void* d_ws, size_t ws_size,
                              hipStream_t stream) {
    const float2* cpoint_loc = (const float2*)d_in[0];
    const float2* alpha      = (const float2*)d_in[1];
    float* out = (float*)d_out;

    rbf_mfma<<<KG * KG, TPB, 0, stream>>>(cpoint_loc, alpha, out);
}